// Round 5
// baseline (466.054 us; speedup 1.0000x reference)
//
#include <hip/hip_runtime.h>

#define C 32
#define NBLOCKS 2048
#define NTHREADS 256
#define ROWS_PER_STEP ((NBLOCKS * NTHREADS) / 8)   // 65536 rows per grid stride
#define FLT_EPS 1.1920928955078125e-07f

typedef float v4f __attribute__((ext_vector_type(4)));

// 8 lanes per row, float4 each -> every load instr is a contiguous 1KB wave
// transaction. Barrier-free hot loop, next-iteration prefetch.
// Argmax: local max (v_max3) + first-match index chain; cross-lane value max in
// 3 b32 shuffles; winner index via ballot byte + one indexed shuffle.
// Only colcount[p] and diag[p] are accumulated (that's all precision needs).
__global__ __launch_bounds__(NTHREADS) void hist_kernel(
    const float* __restrict__ yt,
    const float* __restrict__ yp,
    unsigned int* __restrict__ partial,  // [NBLOCKS][64]: 32 colcounts, 32 diags
    int N)
{
    __shared__ unsigned int colcnt[C];
    __shared__ unsigned int diagcnt[C];
    const int t = threadIdx.x;
    if (t < C) colcnt[t] = 0u;
    else if (t < 2 * C) diagcnt[t - C] = 0u;
    __syncthreads();

    const int lane = t & 63;
    const int lane8 = t & 7;
    const int gb = lane & ~7;        // group base lane within wave

    long long row = (long long)((blockIdx.x * NTHREADS + t) >> 3);
    bool valid = row < N;
    v4f a, b;
    if (valid) {
        a = __builtin_nontemporal_load(((const v4f*)(yt + row * C)) + lane8);
        b = __builtin_nontemporal_load(((const v4f*)(yp + row * C)) + lane8);
    }

    while (valid) {  // validity uniform within each 8-lane group
        const long long nrow = row + ROWS_PER_STEP;
        const bool nvalid = nrow < N;
        v4f na, nb;
        if (nvalid) {  // prefetch next iteration
            na = __builtin_nontemporal_load(((const v4f*)(yt + nrow * C)) + lane8);
            nb = __builtin_nontemporal_load(((const v4f*)(yp + nrow * C)) + lane8);
        }

        // local max of 4 + first-occurrence index (0..3)
        const float lt = fmaxf(fmaxf(a.x, a.y), fmaxf(a.z, a.w));
        const int it4 = (lt == a.x) ? 0 : (lt == a.y) ? 1 : (lt == a.z) ? 2 : 3;
        const float lp = fmaxf(fmaxf(b.x, b.y), fmaxf(b.z, b.w));
        const int ip4 = (lp == b.x) ? 0 : (lp == b.y) ? 1 : (lp == b.z) ? 2 : 3;

        // group max over 8 lanes (values only)
        float mt = lt, mp = lp;
        #pragma unroll
        for (int m = 1; m < 8; m <<= 1) {
            mt = fmaxf(mt, __shfl_xor(mt, m));
            mp = fmaxf(mp, __shfl_xor(mp, m));
        }

        // lowest lane in group holding the max -> first occurrence
        const unsigned long long bt = __ballot(lt == mt);
        const unsigned long long bp = __ballot(lp == mp);
        const int wlT = __ffsll((unsigned long long)((bt >> gb) & 0xFFull)) - 1;
        const int wlP = __ffsll((unsigned long long)((bp >> gb) & 0xFFull)) - 1;
        const int ti = wlT * 4 + __shfl(it4, gb + wlT);
        const int pi = wlP * 4 + __shfl(ip4, gb + wlP);

        if (lane8 == 0) {
            atomicAdd(&colcnt[pi], 1u);
            if (ti == pi) atomicAdd(&diagcnt[pi], 1u);
        }

        row = nrow; valid = nvalid; a = na; b = nb;
    }

    __syncthreads();
    if (t < C) {
        partial[(size_t)blockIdx.x * 64 + t] = colcnt[t];
    } else if (t < 2 * C) {
        partial[(size_t)blockIdx.x * 64 + t] = diagcnt[t - C];
    }
}

// Single block: sum [NBLOCKS][64] partials (coalesced), compute macro precision.
__global__ __launch_bounds__(1024) void finalize_kernel(
    const unsigned int* __restrict__ partial,
    const float* __restrict__ cm_in,
    float* __restrict__ out)
{
    __shared__ float sums[16][64];
    const int tid = threadIdx.x;
    const int col = tid & 63;
    const int kg = tid >> 6;   // 0..15

    unsigned int s = 0;
    #pragma unroll 8
    for (int k = kg * (NBLOCKS / 16); k < (kg + 1) * (NBLOCKS / 16); ++k)
        s += partial[(size_t)k * 64 + col];
    sums[kg][col] = (float)s;
    __syncthreads();

    if (tid < 64) {
        float tot = 0.0f;
        #pragma unroll
        for (int g = 0; g < 16; ++g) tot += sums[g][tid];
        sums[0][tid] = tot;
    }
    __syncthreads();

    if (tid < C) {
        const int j = tid;
        float pp = sums[0][j];       // predicted positives for class j (hist part)
        float tp = sums[0][C + j];   // true positives for class j (hist part)
        float cmcol = 0.0f;
        #pragma unroll
        for (int i = 0; i < C; ++i) cmcol += cm_in[i * C + j];
        pp += cmcol;
        tp += cm_in[j * C + j];
        float prec = tp / (pp + FLT_EPS);
        #pragma unroll
        for (int m = 1; m < C; m <<= 1) prec += __shfl_xor(prec, m);
        if (j == 0) out[0] = prec * (1.0f / (float)C);
    }
}

extern "C" void kernel_launch(void* const* d_in, const int* in_sizes, int n_in,
                              void* d_out, int out_size, void* d_ws, size_t ws_size,
                              hipStream_t stream)
{
    const float* yt = (const float*)d_in[0];
    const float* yp = (const float*)d_in[1];
    const float* cm = (const float*)d_in[2];
    float* out = (float*)d_out;
    const int N = in_sizes[0] / C;

    unsigned int* partial = (unsigned int*)d_ws;  // NBLOCKS*64 u32 = 512 KB, fully overwritten

    hist_kernel<<<NBLOCKS, NTHREADS, 0, stream>>>(yt, yp, partial, N);
    finalize_kernel<<<1, 1024, 0, stream>>>(partial, cm, out);
}